// Round 3
// baseline (3518.695 us; speedup 1.0000x reference)
//
#include <hip/hip_runtime.h>
#include <math.h>

// Problem dims
#define TT 100
#define BB 64
#define II 256
#define HH 512
#define G4H 2048   // 4H
#define G3H 1536   // 3H

// ---- workspace layout (float offsets) ----
// G_T   [T][4H][B]   gates from x@Wih^T + biases, layout [t][j][b]
// DbufT [B][T][3H]   (aliases G_T region after step loop — G_T dead by then)
// Hbuf  [T+1][H][B]  h history transposed; slot 0 = initial_h^T
// Fbuf  [T][H][B]    f gates
// Dbuf  [T][3H][B]   d values (scaled in-place to \tilde{d})
// cT    [H][B]
// xT    [T][I][B]
// WihT  [I][4H]
// (old WhhT region now holds the grid-barrier state)
#define OFF_GT    0
#define OFF_HBUF  13107200
#define OFF_FBUF  16416768
#define OFF_DBUF  19693568
#define OFF_CT    29523968
#define OFF_XT    29556736
#define OFF_WIHT  31195136
#define OFF_BAR   31719424

// ---- output layout (float offsets in d_out) ----
#define O_OUT   0          // outputs [T][B][H]
#define O_CX    3276800    // cx [B][H]
#define O_EVIH  3309568    // ev_ih [B][3H][I]
#define O_EVHH  28475392   // ev_hh [B][3H][H]
#define O_EVB   78807040   // ev_b  [B][3H]

// Generic 64x64 tiled transpose: dst[c][r] = src[r][c]. R,C multiples of 64.
__global__ __launch_bounds__(256) void tp64(const float* __restrict__ src,
                                            float* __restrict__ dst,
                                            int R, int C,
                                            long sstride, long dstride) {
  __shared__ float tile[64][65];
  src += (long)blockIdx.z * sstride;
  dst += (long)blockIdx.z * dstride;
  int r0 = blockIdx.y * 64, c0 = blockIdx.x * 64;
  int tx = threadIdx.x & 15, tq = threadIdx.x >> 4;
#pragma unroll
  for (int p = 0; p < 4; ++p) {
    int rl = p * 16 + tq;
    float4 v = *(const float4*)(src + (long)(r0 + rl) * C + c0 + tx * 4);
    tile[rl][tx * 4 + 0] = v.x; tile[rl][tx * 4 + 1] = v.y;
    tile[rl][tx * 4 + 2] = v.z; tile[rl][tx * 4 + 3] = v.w;
  }
  __syncthreads();
#pragma unroll
  for (int p = 0; p < 4; ++p) {
    int cl = p * 16 + tq;
    float4 v;
    v.x = tile[tx * 4 + 0][cl]; v.y = tile[tx * 4 + 1][cl];
    v.z = tile[tx * 4 + 2][cl]; v.w = tile[tx * 4 + 3][cl];
    *(float4*)(dst + (long)(c0 + cl) * R + r0 + tx * 4) = v;
  }
}

// Tiled TN GEMM: C[m][n] = sum_k A[k][m] * Z[k][n]  (+ bias[m] if BIAS).
// Both operands K-major. 64x64 C-tile, 256 thr, 4x4 outputs/thread.
// ZSHIFT: Z row k maps to (k==0 ? Z0 : Z + (k-1)*ldz)  [h_{t-1} history].
template <int BK, int KTILES, bool BIAS, bool ZSHIFT>
__global__ __launch_bounds__(256) void gemm_tn(
    const float* __restrict__ A, long batchA, int lda,
    const float* __restrict__ Z, long batchZ, int ldz,
    const float* __restrict__ Z0, long batchZ0,
    float* __restrict__ C, long batchC, int ldc,
    const float* __restrict__ bia, const float* __restrict__ bib) {
  __shared__ float As[BK][64];
  __shared__ float Zs[BK][64];
  int tid = threadIdx.x;
  int tn = tid & 15, tm = tid >> 4;
  int m0 = blockIdx.x * 64, n0 = blockIdx.y * 64;
  long bz = blockIdx.z;
  const float* Ab = A + bz * batchA + m0;
  const float* Zb = Z + bz * batchZ + n0;
  const float* Z0b = ZSHIFT ? (Z0 + bz * batchZ0 + n0) : nullptr;
  float acc[4][4] = {};
  for (int kt = 0; kt < KTILES; ++kt) {
    int k0 = kt * BK;
#pragma unroll
    for (int p = tid; p < BK * 64; p += 256) {
      int r = p >> 6, c = p & 63;
      int k = k0 + r;
      As[r][c] = Ab[(long)k * lda + c];
      const float* zr;
      if (ZSHIFT)
        zr = (k == 0) ? Z0b : (Zb + (long)(k - 1) * ldz);
      else
        zr = Zb + (long)k * ldz;
      Zs[r][c] = zr[c];
    }
    __syncthreads();
#pragma unroll 4
    for (int kk = 0; kk < BK; ++kk) {
      float4 a = *(const float4*)&As[kk][tm * 4];
      float4 z = *(const float4*)&Zs[kk][tn * 4];
      float av[4] = {a.x, a.y, a.z, a.w};
      float zv[4] = {z.x, z.y, z.z, z.w};
#pragma unroll
      for (int q = 0; q < 4; ++q)
#pragma unroll
        for (int r = 0; r < 4; ++r)
          acc[q][r] = fmaf(av[q], zv[r], acc[q][r]);
    }
    __syncthreads();
  }
  float* Cb = C + bz * batchC + n0 + tn * 4;
#pragma unroll
  for (int q = 0; q < 4; ++q) {
    int m = m0 + tm * 4 + q;
    float bv = BIAS ? (bia[m] + bib[m]) : 0.f;
    float4 v;
    v.x = acc[q][0] + bv; v.y = acc[q][1] + bv;
    v.z = acc[q][2] + bv; v.w = acc[q][3] + bv;
    *(float4*)(Cb + (long)m * ldc) = v;
  }
}

__global__ void zero_bar(int* bar) {
  if (threadIdx.x < 2) bar[threadIdx.x] = 0;
}

__device__ __forceinline__ void grid_barrier(int* bar, int nblk) {
  __syncthreads();
  if (threadIdx.x == 0) {
    __threadfence();  // device-scope: flush our global writes
    int gen = __hip_atomic_load(bar + 1, __ATOMIC_RELAXED,
                                __HIP_MEMORY_SCOPE_AGENT);
    int arr = __hip_atomic_fetch_add(bar, 1, __ATOMIC_ACQ_REL,
                                     __HIP_MEMORY_SCOPE_AGENT);
    if (arr == nblk - 1) {
      __hip_atomic_store(bar, 0, __ATOMIC_RELAXED, __HIP_MEMORY_SCOPE_AGENT);
      __hip_atomic_store(bar + 1, gen + 1, __ATOMIC_RELEASE,
                         __HIP_MEMORY_SCOPE_AGENT);
    } else {
      while (__hip_atomic_load(bar + 1, __ATOMIC_ACQUIRE,
                               __HIP_MEMORY_SCOPE_AGENT) == gen) {
        __builtin_amdgcn_s_sleep(1);
      }
    }
  }
  __syncthreads();
}

// Persistent LSTM recurrence. 256 blocks x 512 thr (cooperative).
// Block owns hh0 = blockIdx.x*2 .. +1 (8 gate columns). Whh slice in LDS.
// Wave w covers k in [w*64, w*64+64); lane = b. One grid barrier per step.
__global__ __launch_bounds__(512) void lstm_persist(
    const float* __restrict__ G_T, const float* __restrict__ Whh,
    float* __restrict__ Hbuf, const float* __restrict__ c0,
    float* __restrict__ cT, float* __restrict__ Fbuf,
    float* __restrict__ Dbuf, int* bar) {
  __shared__ float Wlds[512][8];   // [k][jj], jj = hl*4 + gate
  __shared__ float red[8][8][64];  // [wave][jj][b]
  __shared__ float gl[8][64];      // [jj][b] summed gates
  int tid = threadIdx.x;
  int lane = tid & 63;
  int w = __builtin_amdgcn_readfirstlane(tid >> 6);
  int hh0 = blockIdx.x * 2;

  // stage Whh slice: Wlds[k][hl*4+g] = Whh[(g*512 + hh0+hl)*512 + k]
#pragma unroll
  for (int row = 0; row < 8; ++row) {
    int hl = row >> 2, g = row & 3;
    Wlds[tid][row] = Whh[((g << 9) + hh0 + hl) * 512 + tid];
  }

  // per-thread cell state (tid < 128): h2 = tid>>6, b = tid&63
  float creg = 0.f;
  if (tid < 128) creg = c0[(tid & 63) * HH + hh0 + (tid >> 6)];
  __syncthreads();

  for (int t = 0; t < TT; ++t) {
    // --- h @ Whh^T partial sums ---
    const float* hp = Hbuf + (long)t * (HH * BB) + (w * 64) * BB + lane;
    const float* wl = &Wlds[w * 64][0];
    float a0 = 0.f, a1 = 0.f, a2 = 0.f, a3 = 0.f;
    float a4 = 0.f, a5 = 0.f, a6 = 0.f, a7 = 0.f;
#pragma unroll 8
    for (int k = 0; k < 64; ++k) {
      float h = hp[k * BB];
      float4 wa = *(const float4*)(wl + k * 8);
      float4 wb = *(const float4*)(wl + k * 8 + 4);
      a0 = fmaf(wa.x, h, a0);
      a1 = fmaf(wa.y, h, a1);
      a2 = fmaf(wa.z, h, a2);
      a3 = fmaf(wa.w, h, a3);
      a4 = fmaf(wb.x, h, a4);
      a5 = fmaf(wb.y, h, a5);
      a6 = fmaf(wb.z, h, a6);
      a7 = fmaf(wb.w, h, a7);
    }
    red[w][0][lane] = a0; red[w][1][lane] = a1;
    red[w][2][lane] = a2; red[w][3][lane] = a3;
    red[w][4][lane] = a4; red[w][5][lane] = a5;
    red[w][6][lane] = a6; red[w][7][lane] = a7;
    __syncthreads();

    // --- reduce + add G_T: thread tid handles jj = tid>>6, b = lane ---
    {
      int jj = w, b = lane;
      int jg = ((jj & 3) << 9) + hh0 + (jj >> 2);  // gate*512 + hh
      float s = G_T[(long)t * (G4H * BB) + (long)jg * BB + b];
#pragma unroll
      for (int ww = 0; ww < 8; ++ww) s += red[ww][jj][b];
      gl[jj][b] = s;
    }
    __syncthreads();

    // --- pointwise (tid < 128) ---
    if (tid < 128) {
      int b = tid & 63, h2 = tid >> 6;
      int hhx = hh0 + h2;
      float ig = 1.f / (1.f + expf(-gl[h2 * 4 + 0][b]));
      float fg = 1.f / (1.f + expf(-gl[h2 * 4 + 1][b]));
      float gg = tanhf(gl[h2 * 4 + 2][b]);
      float og = 1.f / (1.f + expf(-gl[h2 * 4 + 3][b]));
      float co = creg;
      float cy = fg * co + ig * gg;
      creg = cy;
      int idx = hhx * BB + b;
      Hbuf[(long)(t + 1) * (HH * BB) + idx] = og * tanhf(cy);
      Fbuf[(long)t * (HH * BB) + idx] = fg;
      float* dp = Dbuf + (long)t * (G3H * BB) + idx;
      dp[0] = gg * ig * (1.f - ig);
      dp[HH * BB] = co * fg * (1.f - fg);
      dp[2 * HH * BB] = ig * (1.f - gg * gg);
    }
    grid_barrier(bar, 256);
  }

  if (tid < 128) {
    int b = tid & 63, h2 = tid >> 6;
    cT[(hh0 + h2) * BB + b] = creg;
  }
}

// Backward suffix scan: Dbuf[t] *= P_t; also emits ev_b.
__global__ __launch_bounds__(256) void suffix_scale(float* __restrict__ Dbuf,
                                                    const float* __restrict__ Fbuf,
                                                    float* __restrict__ evb) {
  int g = blockIdx.x * 256 + threadIdx.x;
  int b = g & 63, hh = g >> 6;
  float P = 1.f, e0 = 0.f, e1 = 0.f, e2 = 0.f;
#pragma unroll 2
  for (int t = TT - 1; t >= 0; --t) {
    float* dp = Dbuf + (long)t * (G3H * BB) + hh * BB + b;
    float v0 = dp[0] * P, v1 = dp[HH * BB] * P, v2 = dp[2 * HH * BB] * P;
    dp[0] = v0; dp[HH * BB] = v1; dp[2 * HH * BB] = v2;
    e0 += v0; e1 += v1; e2 += v2;
    P *= Fbuf[(long)t * (HH * BB) + hh * BB + b];
  }
  evb[b * G3H + hh] = e0;
  evb[b * G3H + HH + hh] = e1;
  evb[b * G3H + 2 * HH + hh] = e2;
}

extern "C" void kernel_launch(void* const* d_in, const int* in_sizes, int n_in,
                              void* d_out, int out_size, void* d_ws, size_t ws_size,
                              hipStream_t stream) {
  const float* x   = (const float*)d_in[0];  // [T][B][I]
  const float* h0  = (const float*)d_in[1];  // [B][H]
  const float* c0  = (const float*)d_in[2];  // [B][H]
  const float* Wih = (const float*)d_in[3];  // [4H][I]
  const float* Whh = (const float*)d_in[4];  // [4H][H]
  const float* bih = (const float*)d_in[5];
  const float* bhh = (const float*)d_in[6];
  float* out = (float*)d_out;
  float* ws = (float*)d_ws;

  float* G_T   = ws + OFF_GT;
  float* DbufT = ws + OFF_GT;   // aliases G_T (dead after recurrence)
  float* Hbuf  = ws + OFF_HBUF;
  float* Fbuf  = ws + OFF_FBUF;
  float* Dbuf  = ws + OFF_DBUF;
  float* cT    = ws + OFF_CT;
  float* xT    = ws + OFF_XT;
  float* WihT  = ws + OFF_WIHT;
  int*   bar   = (int*)(ws + OFF_BAR);

  // ---- prep transposes ----
  tp64<<<dim3(II / 64, G4H / 64, 1), 256, 0, stream>>>(Wih, WihT, G4H, II, 0, 0);
  tp64<<<dim3(II / 64, 1, TT), 256, 0, stream>>>(x, xT, BB, II, BB * II, BB * II);
  tp64<<<dim3(HH / 64, 1, 1), 256, 0, stream>>>(h0, Hbuf, BB, HH, 0, 0);

  // ---- G = x @ Wih^T + biases, layout [t][j][b] ----
  gemm_tn<64, 4, true, false><<<dim3(G4H / 64, 1, TT), 256, 0, stream>>>(
      WihT, 0, G4H, xT, (long)II * BB, BB, nullptr, 0,
      G_T, (long)G4H * BB, BB, bih, bhh);

  // ---- persistent recurrence (cooperative, 1 grid barrier / step) ----
  zero_bar<<<1, 64, 0, stream>>>(bar);
  {
    const float* a0 = G_T; const float* a1 = Whh; float* a2 = Hbuf;
    const float* a3 = c0; float* a4 = cT; float* a5 = Fbuf; float* a6 = Dbuf;
    int* a7 = bar;
    void* args[] = {&a0, &a1, &a2, &a3, &a4, &a5, &a6, &a7};
    hipLaunchCooperativeKernel((void*)lstm_persist, dim3(256), dim3(512), args,
                               0, stream);
  }

  // ---- backward suffix scaling (+ ev_b) ----
  suffix_scale<<<dim3(HH * BB / 256, 1, 1), 256, 0, stream>>>(Dbuf, Fbuf,
                                                              out + O_EVB);

  // ---- Dbuf [T*3H][B] -> DbufT [B][T*3H] ----
  tp64<<<dim3(1, TT * G3H / 64, 1), 256, 0, stream>>>(Dbuf, DbufT, TT * G3H, BB,
                                                      0, 0);

  // ---- outputs + cx ----
  tp64<<<dim3(1, HH / 64, TT), 256, 0, stream>>>(Hbuf + HH * BB, out + O_OUT,
                                                 HH, BB, HH * BB, HH * BB);
  tp64<<<dim3(1, HH / 64, 1), 256, 0, stream>>>(cT, out + O_CX, HH, BB, 0, 0);

  // ---- ev_ih[b][j][i] = sum_t DbufT[b][t][j] * x[t][b][i], K=100 ----
  gemm_tn<20, 5, false, false><<<dim3(G3H / 64, II / 64, BB), 256, 0, stream>>>(
      DbufT, (long)TT * G3H, G3H, x, (long)II, (long)BB * II, nullptr, 0,
      out + O_EVIH, (long)G3H * II, II, nullptr, nullptr);

  // ---- ev_hh[b][j][k] = sum_t DbufT[b][t][j] * h_{t-1}[b][k], K=100 ----
  gemm_tn<20, 5, false, true><<<dim3(G3H / 64, HH / 64, BB), 256, 0, stream>>>(
      DbufT, (long)TT * G3H, G3H, out + O_OUT, (long)HH, (long)BB * HH,
      h0, (long)HH,
      out + O_EVHH, (long)G3H * HH, HH, nullptr, nullptr);
}